// Round 3
// baseline (311.365 us; speedup 1.0000x reference)
//
#include <hip/hip_runtime.h>

typedef __attribute__((ext_vector_type(8))) short bf16x8;
typedef __attribute__((ext_vector_type(4))) float f32x4;

__device__ __forceinline__ unsigned short f2bf(float f) {
  unsigned int u = __builtin_bit_cast(unsigned int, f);
  u += 0x7fffu + ((u >> 16) & 1u);   // round-to-nearest-even
  return (unsigned short)(u >> 16);
}

// v_cvt_pk_bf16_f32: D[15:0]=bf16(lo), D[31:16]=bf16(hi), RNE (T12 recipe)
__device__ __forceinline__ unsigned int cvt_pk_bf16(float lo, float hi) {
  unsigned int r;
  asm("v_cvt_pk_bf16_f32 %0, %1, %2" : "=v"(r) : "v"(lo), "v"(hi));
  return r;
}

typedef const __attribute__((address_space(1))) unsigned int* as1_u32p;
typedef __attribute__((address_space(3))) unsigned int* as3_u32p;
__device__ __forceinline__ void glds16(const void* g, void* l) {
  __builtin_amdgcn_global_load_lds((as1_u32p)g, (as3_u32p)l, 16, 0, 0);
}

// ---------------------------------------------------------------------------
// K0: bulk fp32 -> bf16 convert (8 elems/thread)
// ---------------------------------------------------------------------------
__global__ __launch_bounds__(256) void cvt_kernel(const float* __restrict__ X,
                                                  unsigned short* __restrict__ Y) {
  const long long i = ((long long)blockIdx.x * 256 + threadIdx.x) * 8;
  float4 a = *reinterpret_cast<const float4*>(X + i);
  float4 b = *reinterpret_cast<const float4*>(X + i + 4);
  bf16x8 t;
  t[0] = (short)f2bf(a.x); t[1] = (short)f2bf(a.y);
  t[2] = (short)f2bf(a.z); t[3] = (short)f2bf(a.w);
  t[4] = (short)f2bf(b.x); t[5] = (short)f2bf(b.y);
  t[6] = (short)f2bf(b.z); t[7] = (short)f2bf(b.w);
  *reinterpret_cast<bf16x8*>(Y + i) = t;
}

// ---------------------------------------------------------------------------
// K0t: fp32 [R][C] -> bf16 [C][R] transpose (32x32 tiles)
// ---------------------------------------------------------------------------
__global__ __launch_bounds__(256) void transpose_bf16_kernel(
    const float* __restrict__ S, unsigned short* __restrict__ D, int R, int C) {
  __shared__ float T[32][33];
  const int bx = blockIdx.x * 32;  // col tile
  const int by = blockIdx.y * 32;  // row tile
  const int tx = threadIdx.x & 31, ty = threadIdx.x >> 5;
#pragma unroll
  for (int k = 0; k < 4; ++k)
    T[ty + 8 * k][tx] = S[(size_t)(by + ty + 8 * k) * C + bx + tx];
  __syncthreads();
#pragma unroll
  for (int k = 0; k < 4; ++k)
    D[(size_t)(bx + ty + 8 * k) * R + by + tx] = f2bf(T[tx][ty + 8 * k]);
}

// ---------------------------------------------------------------------------
// K0m: mask bit-pack to u32 words via ballot.
// Mb[g>>5] bit (g&31) = (mask[g] != 0), g = (s*256+row)*256 + k.
// i.e. Mb[(s*256+row)*8 + w] bit b = mask[s][row][w*32+b].  512 KiB total.
// ---------------------------------------------------------------------------
__global__ __launch_bounds__(256) void pack_mask_kernel(const int* __restrict__ mask,
                                                        unsigned int* __restrict__ Mb) {
  const int g = blockIdx.x * 256 + threadIdx.x;
  const unsigned long long bal = __ballot(mask[g] != 0);
  const int lane = threadIdx.x & 63;
  if ((lane & 31) == 0)
    Mb[g >> 5] = (unsigned int)(bal >> (lane & 32));
}

// ---------------------------------------------------------------------------
// K1/K3: bf16 GEMM  C[M][N] = A[M][K] * Bt[N][K]^T (+bias), fp32 accum.
// 128x128 tile, BK=32, glds width-16 staging, now DOUBLE-BUFFERED with
// minimum-2-phase schedule (T3-lite): stage(t+1) issued before compute(t),
// ONE barrier per K-step (was two).  Race-free: buf[cur^1] was last read in
// iter t-1, whose reads completed before the end-of-(t-1) barrier; stage(t+1)
// drains at end-of-t barrier (implicit vmcnt(0)).
// ---------------------------------------------------------------------------
template <bool C_F32>
__global__ __launch_bounds__(256) void gemm_bt(
    const unsigned short* __restrict__ A,   // [M][K] bf16
    const unsigned short* __restrict__ Bt,  // [N][K] bf16
    void* __restrict__ Cv,
    const float* __restrict__ bias,         // [N] fp32 (C_F32 only)
    int M, int N, int K)
{
  __shared__ __align__(16) unsigned short As[2][128 * 32];
  __shared__ __align__(16) unsigned short Bs[2][128 * 32];

  const int tid  = threadIdx.x;
  const int bm   = blockIdx.x * 128;
  const int bn   = blockIdx.y * 128;
  const int lane = tid & 63;
  const int wave = tid >> 6;
  const int wr   = (wave >> 1) * 64;
  const int wc   = (wave & 1) * 64;
  const int l15  = lane & 15;
  const int quad = lane >> 4;

  f32x4 acc[4][4];
#pragma unroll
  for (int r = 0; r < 4; ++r)
#pragma unroll
    for (int c = 0; c < 4; ++c) {
      f32x4 z = {0.f, 0.f, 0.f, 0.f};
      acc[r][c] = z;
    }

  // per-lane global srcs; wave-uniform LDS dests (dest = base + lane*16B)
  const unsigned short* gA0 = A  + (size_t)(bm + wave * 16 + (lane >> 2)) * K + (lane & 3) * 8;
  const unsigned short* gA1 = gA0 + (size_t)64 * K;
  const unsigned short* gB0 = Bt + (size_t)(bn + wave * 16 + (lane >> 2)) * K + (lane & 3) * 8;
  const unsigned short* gB1 = gB0 + (size_t)64 * K;
  const int woff = wave * 512;

  // prologue: stage tile 0 into buf 0
  glds16(gA0, &As[0][woff]);
  glds16(gA1, &As[0][2048 + woff]);
  glds16(gB0, &Bs[0][woff]);
  glds16(gB1, &Bs[0][2048 + woff]);
  __syncthreads();

  const int nt = K >> 5;
  for (int t = 0; t < nt; ++t) {
    const int cur = t & 1;
    if (t + 1 < nt) {
      const int kk = (t + 1) << 5;
      unsigned short* an = As[cur ^ 1];
      unsigned short* bn_ = Bs[cur ^ 1];
      glds16(gA0 + kk, an + woff);
      glds16(gA1 + kk, an + 2048 + woff);
      glds16(gB0 + kk, bn_ + woff);
      glds16(gB1 + kk, bn_ + 2048 + woff);
    }
    bf16x8 af[4], bf[4];
#pragma unroll
    for (int i = 0; i < 4; ++i) {
      af[i] = *reinterpret_cast<const bf16x8*>(&As[cur][(wr + i * 16 + l15) * 32 + quad * 8]);
      bf[i] = *reinterpret_cast<const bf16x8*>(&Bs[cur][(wc + i * 16 + l15) * 32 + quad * 8]);
    }
#pragma unroll
    for (int rt = 0; rt < 4; ++rt)
#pragma unroll
      for (int ct = 0; ct < 4; ++ct)
        acc[rt][ct] = __builtin_amdgcn_mfma_f32_16x16x32_bf16(af[rt], bf[ct], acc[rt][ct], 0, 0, 0);
    __syncthreads();
  }

  // epilogue: D[row=quad*4+i][col=l15] per 16x16 tile (proven layout)
#pragma unroll
  for (int rt = 0; rt < 4; ++rt)
#pragma unroll
    for (int ct = 0; ct < 4; ++ct)
#pragma unroll
      for (int i = 0; i < 4; ++i) {
        const int row = bm + wr + rt * 16 + quad * 4 + i;
        const int col = bn + wc + ct * 16 + l15;
        const float v = acc[rt][ct][i];
        if constexpr (C_F32) {
          ((float*)Cv)[(size_t)row * N + col] = v + bias[col];
        } else {
          ((unsigned short*)Cv)[(size_t)row * N + col] = f2bf(v);
        }
      }
}

// ---------------------------------------------------------------------------
// K2: masked softmax attention — SWAPPED QK^T + permuted-k PV.
//
//   sim[ct] = mfma(kf, qf): lane holds S[q=qbase+l15][k=ct*16+quad*4+i]
//   -> softmax row is lane-local + 2 shfl_xor (16,32) across quads.
//   PV uses k-slot permutation pi(quad,j) = c*32 + (j<4 ? 4q+j : 16+4q+j-4)
//   (bijective on [0,32)): A-frag = cvt_pk pairs of own sim (NO LDS, NO
//   shuffle); V B-frag gathered with the same pi.  1/lsum folded into P.
//   qb loop has ZERO barriers and ZERO LDS traffic except kf ds_reads.
//   LDS: Ks 16384 + Vs 256*36*2 = 18432 -> 34816 B total.
//   Vs stride 36: bv gather quad bank offsets {0,8,16,24} -> conflict-free.
// ---------------------------------------------------------------------------
#define SCALE_F 0.17677669529663689f

__global__ __launch_bounds__(256) void attn_kernel(
    const unsigned short* __restrict__ QKV,   // [t][768] bf16: Q|K|V
    const unsigned int* __restrict__ Mb,      // [64*256][8] u32 bit-packed mask
    unsigned short* __restrict__ Aout)        // [65536][256] bf16
{
  __shared__ __align__(16) unsigned short Ks[256 * 32];  // XOR-swizzled, 16384 B
  __shared__ __align__(16) unsigned short Vs[256 * 36];  // stride 36, 18432 B

  const int blk  = blockIdx.x;   // 0..2047
  const int h    = blk & 7;
  const int sb   = blk >> 3;
  const int s    = sb >> 2;
  const int t0   = sb << 8;
  const int tid  = threadIdx.x;
  const int lane = tid & 63;
  const int wave = tid >> 6;
  const int l15  = lane & 15;
  const int quad = lane >> 4;

  {
    const unsigned short* kp = QKV + (size_t)(t0 + tid) * 768 + 256 + h * 32;
    const unsigned short* vp = kp + 256;
    const int sw = (tid >> 1) & 3;              // K row-granule swizzle
    unsigned short* kd = Ks + tid * 32;
    unsigned short* vd = Vs + tid * 36;
#pragma unroll
    for (int g = 0; g < 4; ++g)
      *reinterpret_cast<uint4*>(kd + ((g ^ sw) << 3)) = *reinterpret_cast<const uint4*>(kp + g * 8);
#pragma unroll
    for (int i = 0; i < 16; ++i)   // 16 x 4B word copies (base tid*72 B is 8B-aligned)
      *reinterpret_cast<unsigned int*>(vd + i * 2) = *reinterpret_cast<const unsigned int*>(vp + i * 2);
  }
  __syncthreads();

  // V B-frags with permuted k-slots: slot j of k-tile c holds actual
  // k = c*32 + (j<4 ? quad*4+j : 16+quad*4+j-4).
  bf16x8 bv[2][8];
#pragma unroll
  for (int dt = 0; dt < 2; ++dt)
#pragma unroll
    for (int c = 0; c < 8; ++c) {
      bf16x8 v;
#pragma unroll
      for (int j = 0; j < 8; ++j) {
        const int row = c * 32 + ((j < 4) ? (quad * 4 + j) : (16 + quad * 4 + (j - 4)));
        v[j] = (short)Vs[row * 36 + dt * 16 + l15];
      }
      bv[dt][c] = v;
    }

  const int swr = (l15 >> 1) & 3;   // K-read granule swizzle (row = ct*16+l15)

  for (int qb = 0; qb < 4; ++qb) {
    const int qbase = wave * 64 + qb * 16;

    // B-frag: Q[qbase+l15][quad*8+j] (identical load to before)
    bf16x8 qf = *reinterpret_cast<const bf16x8*>(
        QKV + (size_t)(t0 + qbase + l15) * 768 + h * 32 + quad * 8);

    // mask bits for this lane's q-row, pre-shifted by quad*4 so every
    // bit test is a compile-time position: bit for sim[ct][i] is
    // msk[ct>>1] >> ((ct&1)*16 + i).
    unsigned int msk[8];
    {
      const unsigned int* mrow = Mb + (((size_t)s * 256 + qbase + l15) << 3);
      uint4 m0 = *reinterpret_cast<const uint4*>(mrow);
      uint4 m1 = *reinterpret_cast<const uint4*>(mrow + 4);
      const int qs = quad * 4;
      msk[0] = m0.x >> qs; msk[1] = m0.y >> qs; msk[2] = m0.z >> qs; msk[3] = m0.w >> qs;
      msk[4] = m1.x >> qs; msk[5] = m1.y >> qs; msk[6] = m1.z >> qs; msk[7] = m1.w >> qs;
    }

    // swapped QK^T: sim[ct][i] = S[q=qbase+l15][k=ct*16+quad*4+i]
    f32x4 sim[16];
#pragma unroll
    for (int ct = 0; ct < 16; ++ct) {
      bf16x8 kf = *reinterpret_cast<const bf16x8*>(
          &Ks[(ct * 16 + l15) * 32 + ((quad ^ swr) << 3)]);
      f32x4 z = {0.f, 0.f, 0.f, 0.f};
      sim[ct] = __builtin_amdgcn_mfma_f32_16x16x32_bf16(kf, qf, z, 0, 0, 0);
    }

    // scale + mask + row max (lane-local 64 + 2 shfl)
    float mx = -3.0e38f;
#pragma unroll
    for (int ct = 0; ct < 16; ++ct)
#pragma unroll
      for (int i = 0; i < 4; ++i) {
        float v = sim[ct][i] * SCALE_F;
        if (!((msk[ct >> 1] >> ((ct & 1) * 16 + i)) & 1u)) v = -1.0e10f;
        sim[ct][i] = v;
        mx = fmaxf(mx, v);
      }
    mx = fmaxf(mx, __shfl_xor(mx, 16, 64));
    mx = fmaxf(mx, __shfl_xor(mx, 32, 64));

    // exp + row sum
    float sum = 0.f;
#pragma unroll
    for (int ct = 0; ct < 16; ++ct)
#pragma unroll
      for (int i = 0; i < 4; ++i) {
        float e = __expf(sim[ct][i] - mx);
        sim[ct][i] = e;
        sum += e;
      }
    sum += __shfl_xor(sum, 16, 64);
    sum += __shfl_xor(sum, 32, 64);
    const float rl = 1.0f / sum;

    // PV: A-frag element e of tile c = P[q][pi(quad,e)] = sim[2c+(e>>2)][e&3]*rl
    f32x4 o0 = {0.f, 0.f, 0.f, 0.f};
    f32x4 o1 = {0.f, 0.f, 0.f, 0.f};
#pragma unroll
    for (int c = 0; c < 8; ++c) {
      uint4 u;
      u.x = cvt_pk_bf16(sim[2 * c][0] * rl,     sim[2 * c][1] * rl);
      u.y = cvt_pk_bf16(sim[2 * c][2] * rl,     sim[2 * c][3] * rl);
      u.z = cvt_pk_bf16(sim[2 * c + 1][0] * rl, sim[2 * c + 1][1] * rl);
      u.w = cvt_pk_bf16(sim[2 * c + 1][2] * rl, sim[2 * c + 1][3] * rl);
      bf16x8 pf = __builtin_bit_cast(bf16x8, u);
      o0 = __builtin_amdgcn_mfma_f32_16x16x32_bf16(pf, bv[0][c], o0, 0, 0, 0);
      o1 = __builtin_amdgcn_mfma_f32_16x16x32_bf16(pf, bv[1][c], o1, 0, 0, 0);
    }

    // D: lane holds O[q=qbase+quad*4+i][d=dt*16+l15], already normalized
#pragma unroll
    for (int i = 0; i < 4; ++i) {
      const size_t row = (size_t)t0 + qbase + quad * 4 + i;
      Aout[row * 256 + h * 32 + l15]      = f2bf(o0[i]);
      Aout[row * 256 + h * 32 + 16 + l15] = f2bf(o1[i]);
    }
  }
}

// ---------------------------------------------------------------------------
// Memory plan:
//   ws[0, 96MiB)        QKV  (live K1->attn); WoutT transposed into ws[0]
//                             AFTER attn (QKV dead) for K3.
//   ws[96MiB, 128MiB)   Xbf  (live cvt->K1), then Amid aliases it (attn->K3).
//   d_out[0, 384KB)     WqkvT scratch (live ->K1; K1 only READS d_out).
//   d_out[32MiB, 32.5MiB) Mbits bit-packed mask (live pack->attn).
//   K3 overwrites all of d_out at the end.
// ---------------------------------------------------------------------------
extern "C" void kernel_launch(void* const* d_in, const int* in_sizes, int n_in,
                              void* d_out, int out_size, void* d_ws, size_t ws_size,
                              hipStream_t stream) {
  const float* X    = (const float*)d_in[0];  // [65536][256] fp32
  const int*   mask = (const int*)d_in[1];    // [64][256][256] int32
  const float* Wqkv = (const float*)d_in[2];  // [256][768] fp32
  const float* Wout = (const float*)d_in[3];  // [256][256] fp32
  const float* bout = (const float*)d_in[4];  // [256] fp32
  float*       outp = (float*)d_out;          // [65536][256] fp32

  unsigned short* QKV   = (unsigned short*)d_ws;       // 96 MiB
  unsigned short* Xbf   = QKV + (size_t)65536 * 768;   // 32 MiB
  unsigned short* Amid  = Xbf;                         // alias: Xbf dead after K1
  unsigned short* WoutT = QKV;                         // alias: QKV dead after attn
  unsigned short* WqkvT = (unsigned short*)d_out;      // d_out scratch, dead before K3
  unsigned int*   Mbits = (unsigned int*)((char*)d_out + ((size_t)32 << 20));

  dim3 blk(256);
  cvt_kernel<<<dim3(8192), blk, 0, stream>>>(X, Xbf);
  transpose_bf16_kernel<<<dim3(24, 8), blk, 0, stream>>>(Wqkv, WqkvT, 256, 768);
  pack_mask_kernel<<<dim3(16384), blk, 0, stream>>>(mask, Mbits);

  gemm_bt<false><<<dim3(512, 6), blk, 0, stream>>>(Xbf, WqkvT, (void*)QKV, nullptr, 65536, 768, 256);
  attn_kernel<<<dim3(2048), blk, 0, stream>>>(QKV, Mbits, Amid);

  transpose_bf16_kernel<<<dim3(8, 8), blk, 0, stream>>>(Wout, WoutT, 256, 256);
  gemm_bt<true><<<dim3(512, 2), blk, 0, stream>>>(Amid, WoutT, (void*)outp, bout, 65536, 256, 256);
}